// Round 3
// baseline (76.352 us; speedup 1.0000x reference)
//
#include <hip/hip_runtime.h>
#include <math.h>

#define FIN 128
#define FOUT 128
#define RB 64            // rows per block
#define LSTR 129         // LDS row stride for float arrays (pad +1)
#define CSTR 132         // LDS row stride for c-bytes (33 dwords -> conflict-free)

// 16-byte gather window is only dword-aligned (c is data-dependent); gfx9+
// global_load_dwordx4 is legal/fast at 4B alignment -> one VMEM instr per window.
typedef float v4f __attribute__((ext_vector_type(4), aligned(4)));

// Block: 1024 threads = 16 waves = 4 oh-groups x 4 K-splits.
// Grid: 8 o-blocks x 32 row-blocks = 256 blocks -> 16 waves/CU, 4 waves/SIMD.
__global__ __launch_bounds__(1024) void kan_fwd(
    const float* __restrict__ x,
    const float* __restrict__ bw,
    const float* __restrict__ sw,
    float* __restrict__ out)
{
    __shared__ float smem[2 * RB * LSTR];        // s_u | s_s; reused as reduce buf
    __shared__ unsigned char s_c[RB * CSTR];     // clipped floor index per (row, feat)
    float* s_u = smem;
    float* s_s = smem + RB * LSTR;

    const int tid = threadIdx.x;
    const int nl  = tid & 63;                    // lane = row within block
    const int w   = __builtin_amdgcn_readfirstlane(tid >> 6);  // wave id 0..15
    const int ohg = w & 3;                       // oh sub-group 0..3
    const int ks  = w >> 2;                      // K-split 0..3
    const int rb  = blockIdx.y;                  // 0..31
    const int ob  = blockIdx.x;                  // 0..7
    const int n0  = rb * RB;

    const float G0 = -2.2f;                      // GRID_MIN - 3*H
    const float Hh = 0.4f;

    // ---- staging: silu, u, and clipped floor idx for 64 rows x 128 feats ----
    for (int e = tid; e < RB * FIN; e += 1024) {
        int r = e >> 7;
        int i = e & 127;
        float xv = x[(n0 + r) * FIN + i];
        float si = xv / (1.0f + expf(-xv));
        float xn = fminf(fmaxf(xv, -1.0f), 1.0f);
        float t  = (xn - G0) / Hh;               // true division, matches XLA
        float u  = t - floorf(t);                // UNclipped floor, per reference
        int idx  = (int)floorf(t);
        idx = min(max(idx, 3), 7);
        s_u[r * LSTR + i] = u;
        s_s[r * LSTR + i] = si;
        s_c[r * CSTR + i] = (unsigned char)(idx - 3);
    }

    const int oh = __builtin_amdgcn_readfirstlane(ob * 4 + ohg);  // 0..31

    __syncthreads();

    // ---- per-thread gather offsets from LDS (c depends on x[n, m], m = oh+32b) ----
    const int off0 = (oh +  0) * 8 + s_c[nl * CSTR + oh +  0];
    const int off1 = (oh + 32) * 8 + s_c[nl * CSTR + oh + 32];
    const int off2 = (oh + 64) * 8 + s_c[nl * CSTR + oh + 64];
    const int off3 = (oh + 96) * 8 + s_c[nl * CSTR + oh + 96];

    const float* bw0 = bw + (oh * 4 + 0) * FIN;  // uniform rows -> s_loads
    const float* bw1 = bw + (oh * 4 + 1) * FIN;
    const float* bw2 = bw + (oh * 4 + 2) * FIN;
    const float* bw3 = bw + (oh * 4 + 3) * FIN;

    v4f acc = {0.f, 0.f, 0.f, 0.f};

    const int a0 = ks * 32;
#pragma unroll 4
    for (int j = 0; j < 32; ++j) {
        const int a = a0 + j;
        float u  = s_u[nl * LSTR + a];
        float si = s_s[nl * LSTR + a];

        const float* sa = sw + a * 1024;
        v4f g0 = *(const v4f*)(sa + off0);       // one global_load_dwordx4 each
        v4f g1 = *(const v4f*)(sa + off1);
        v4f g2 = *(const v4f*)(sa + off2);
        v4f g3 = *(const v4f*)(sa + off3);

        float u2 = u * u;
        float u3 = u2 * u;
        float om = 1.0f - u;
        float b0 = om * om * om * (1.0f / 6.0f);
        float b1 = 0.5f * u3 - u2 + (2.0f / 3.0f);
        float b2 = -0.5f * u3 + 0.5f * u2 + 0.5f * u + (1.0f / 6.0f);
        float b3 = u3 * (1.0f / 6.0f);

        acc += b0 * g0;
        acc += b1 * g1;
        acc += b2 * g2;
        acc += b3 * g3;

        v4f bv = {bw0[a], bw1[a], bw2[a], bw3[a]};  // wave-uniform -> s_loads
        acc += si * bv;
    }

    // ---- cross-split reduction via LDS (alias smem; s_u/s_s dead now) ----
    __syncthreads();                              // all reads of s_u/s_s done
    float* red = smem;                            // 1024 threads x 4 floats = 16 KB
    ((float4*)red)[tid] = make_float4(acc.x, acc.y, acc.z, acc.w);
    __syncthreads();

    if (tid < 256) {
        int ohg2  = tid >> 6;
        int lane2 = tid & 63;
        float4 r0 = ((float4*)red)[0 * 256 + tid];
        float4 r1 = ((float4*)red)[1 * 256 + tid];
        float4 r2 = ((float4*)red)[2 * 256 + tid];
        float4 r3 = ((float4*)red)[3 * 256 + tid];
        float4 o4;
        o4.x = r0.x + r1.x + r2.x + r3.x;
        o4.y = r0.y + r1.y + r2.y + r3.y;
        o4.z = r0.z + r1.z + r2.z + r3.z;
        o4.w = r0.w + r1.w + r2.w + r3.w;
        *(float4*)(out + (n0 + lane2) * FOUT + (ob * 4 + ohg2) * 4) = o4;
    }
}

extern "C" void kernel_launch(void* const* d_in, const int* in_sizes, int n_in,
                              void* d_out, int out_size, void* d_ws, size_t ws_size,
                              hipStream_t stream) {
    const float* x  = (const float*)d_in[0];
    const float* bw = (const float*)d_in[1];
    const float* sw = (const float*)d_in[2];
    float* out = (float*)d_out;
    dim3 grid(8, 32);   // 8 o-blocks x 32 row-blocks
    kan_fwd<<<grid, dim3(1024), 0, stream>>>(x, bw, sw, out);
}

// Round 4
// 70.695 us; speedup vs baseline: 1.0800x; 1.0800x over previous
//
#include <hip/hip_runtime.h>
#include <hip/hip_bf16.h>
#include <math.h>

typedef __attribute__((ext_vector_type(8))) short short8;     // bf16x8 MFMA frag
typedef __attribute__((ext_vector_type(4))) float floatx4;    // fp32x4 acc
typedef float v4fu __attribute__((ext_vector_type(4), aligned(4)));

// ---- workspace layout (bytes), total ~12.6 MB ----
#define WS_S    0u          // bf16 [2048][128]        silu(x)
#define WS_P    524288u     // bf16 [4][2048][128]     bspl basis b0..b3
#define WS_BT   2621440u    // bf16 [1152][128]        B^T: rows j<1024 = sw cols; rows 1024+o = bw rows
#define WS_C    2916352u    // u8   [2048][128]        clipped floor idx c in 0..4
#define WS_T    3178496u    // f32  [2048][1152]       GEMM result

// ============ kernel 1: prep (basis, silu, c, bf16 casts, sw transpose) ============
__global__ __launch_bounds__(256) void kan_prep(
    const float* __restrict__ x, const float* __restrict__ bw,
    const float* __restrict__ sw, unsigned char* __restrict__ ws)
{
    __hip_bfloat16* S  = (__hip_bfloat16*)(ws + WS_S);
    __hip_bfloat16* P  = (__hip_bfloat16*)(ws + WS_P);
    __hip_bfloat16* Bt = (__hip_bfloat16*)(ws + WS_BT);
    unsigned char*  cb = ws + WS_C;
    int g = blockIdx.x * 256 + threadIdx.x;
    if (g < 262144) {                       // per (n, i): basis/silu/c
        float xv = x[g];
        float si = xv / (1.0f + expf(-xv));
        float xn = fminf(fmaxf(xv, -1.0f), 1.0f);
        float t  = (xn + 2.2f) / 0.4f;      // (xn - G0)/H, exact same as verified fp32 kernel
        float u  = t - floorf(t);
        int idx  = (int)floorf(t);
        idx = min(max(idx, 3), 7);
        cb[g] = (unsigned char)(idx - 3);
        float u2 = u*u, u3 = u2*u, om = 1.0f - u;
        float b0 = om*om*om*(1.0f/6.0f);
        float b1 = 0.5f*u3 - u2 + (2.0f/3.0f);
        float b2 = -0.5f*u3 + 0.5f*u2 + 0.5f*u + (1.0f/6.0f);
        float b3 = u3*(1.0f/6.0f);
        S[g] = __float2bfloat16(si);
        P[0*262144 + g] = __float2bfloat16(b0);
        P[1*262144 + g] = __float2bfloat16(b1);
        P[2*262144 + g] = __float2bfloat16(b2);
        P[3*262144 + g] = __float2bfloat16(b3);
    } else if (g < 262144 + 131072) {       // sw transpose: Bt[j][a] = sw[a*1024+j]
        int g2 = g - 262144;
        int a = g2 >> 10, j = g2 & 1023;    // coalesced read of sw[g2]
        Bt[j*128 + a] = __float2bfloat16(sw[g2]);
    } else if (g < 262144 + 131072 + 16384) {  // Bt[1024+o][a] = bw[o][a]
        int g3 = g - 393216;
        Bt[131072 + g3] = __float2bfloat16(bw[g3]);
    }
}

// ============ kernel 2: bf16 MFMA GEMM, T[2048][1152] = A_group @ Bt^T ============
// block 256 thr = 4 waves; tile M=32 x N=64; K=128 in one staging pass.
__global__ __launch_bounds__(256) void kan_gemm(unsigned char* __restrict__ ws)
{
    __shared__ __align__(16) __hip_bfloat16 sA[32 * 128];
    __shared__ __align__(16) __hip_bfloat16 sB[64 * 128];
    const int tid = threadIdx.x;
    const int n0  = blockIdx.x * 32;
    const int j0  = blockIdx.y * 64;
    // column group selects A-operand: P_b for j<1024 (b = j0>>8), S for base cols
    const __hip_bfloat16* Ap = (const __hip_bfloat16*)(ws + ((j0 >= 1024) ? WS_S : (WS_P + (unsigned)(j0 >> 8) * 524288u)));
    const __hip_bfloat16* Bp = (const __hip_bfloat16*)(ws + WS_BT);

#pragma unroll
    for (int i = 0; i < 2; ++i) {           // stage A: 32x128 bf16 (8 KB)
        int c = tid + 256*i, r = c >> 4, k8 = c & 15;
        *(uint4*)(sA + r*128 + k8*8) = *(const uint4*)(Ap + (n0 + r)*128 + k8*8);
    }
#pragma unroll
    for (int i = 0; i < 4; ++i) {           // stage B^T: 64x128 bf16 (16 KB)
        int c = tid + 256*i, r = c >> 4, k8 = c & 15;
        *(uint4*)(sB + r*128 + k8*8) = *(const uint4*)(Bp + (j0 + r)*128 + k8*8);
    }
    __syncthreads();

    const int w = tid >> 6, l = tid & 63;
    const int mt = w & 1, nth = w >> 1;     // wave -> (m-tile, n-half)
    const int m = l & 15, q = l >> 4;
    floatx4 acc0 = {0.f,0.f,0.f,0.f}, acc1 = {0.f,0.f,0.f,0.f};
    // A-frag: A[row = l&15][k = q*8 + j]; B-frag: B[k = q*8 + j][col = l&15] from Bt rows
    const int arow  = (mt*16      + m)*128 + q*8;
    const int brow0 = (nth*32     + m)*128 + q*8;
    const int brow1 = (nth*32 + 16 + m)*128 + q*8;
#pragma unroll
    for (int kk = 0; kk < 4; ++kk) {
        short8 a  = *(const short8*)(sA + arow  + kk*32);
        short8 b0 = *(const short8*)(sB + brow0 + kk*32);
        short8 b1 = *(const short8*)(sB + brow1 + kk*32);
        acc0 = __builtin_amdgcn_mfma_f32_16x16x32_bf16(a, b0, acc0, 0, 0, 0);
        acc1 = __builtin_amdgcn_mfma_f32_16x16x32_bf16(a, b1, acc1, 0, 0, 0);
    }
    // C/D layout (m89-verified): col = l&15, row = q*4 + reg
    float* T = (float*)(ws + WS_T);
    const int row  = n0 + mt*16 + q*4;
    const int col0 = j0 + nth*32 + m;
#pragma unroll
    for (int r = 0; r < 4; ++r) {
        T[(row + r)*1152 + col0]      = acc0[r];
        T[(row + r)*1152 + col0 + 16] = acc1[r];
    }
}

// ============ kernel 3: gather epilogue ============
// out[n, 4*oh+ol] = T[n,1024+4oh+ol] + sum_b T[n, 256b + 8*oh + c[n,32b+oh] + ol]
__global__ __launch_bounds__(256) void kan_epi(const unsigned char* __restrict__ ws,
                                               float* __restrict__ out)
{
    int g = blockIdx.x * 256 + threadIdx.x;   // 65536 threads: (n, oh)
    int n = g >> 5, oh = g & 31;
    const unsigned char* cb = ws + WS_C + n*128;
    const float* Tr = (const float*)(ws + WS_T) + n*1152;
    v4fu acc = *(const v4fu*)(Tr + 1024 + 4*oh);
#pragma unroll
    for (int b = 0; b < 4; ++b) {
        int c = cb[32*b + oh];
        acc += *(const v4fu*)(Tr + 256*b + 8*oh + c);   // dword-aligned dwordx4
    }
    *(v4fu*)(out + n*128 + 4*oh) = acc;
}

extern "C" void kernel_launch(void* const* d_in, const int* in_sizes, int n_in,
                              void* d_out, int out_size, void* d_ws, size_t ws_size,
                              hipStream_t stream) {
    const float* x  = (const float*)d_in[0];
    const float* bw = (const float*)d_in[1];
    const float* sw = (const float*)d_in[2];
    float* out = (float*)d_out;
    unsigned char* ws = (unsigned char*)d_ws;
    kan_prep<<<dim3(1600), dim3(256), 0, stream>>>(x, bw, sw, ws);
    kan_gemm<<<dim3(64, 18), dim3(256), 0, stream>>>(ws);
    kan_epi <<<dim3(256), dim3(256), 0, stream>>>(ws, out);
}